// Round 2
// baseline (979.390 us; speedup 1.0000x reference)
//
#include <hip/hip_runtime.h>
#include <math.h>

#define N_NODES 50000
#define DIM 64
#define NE 800000
#define NSCAN_BLOCKS ((N_NODES + 255) / 256)   // 196

// ---------------------------------------------------------------------------
// ws layout:
//   Q       : N*DIM floats
//   K       : N*DIM floats
//   V       : N*DIM floats
//   attn    : NE floats
//   counts  : N ints
//   offsets : N+1 ints
//   cursor  : N ints
//   bsums   : 256 ints
//   bucket  : NE ints
//   g_max (uint), g_sum (float)
// total ~46 MB
// ---------------------------------------------------------------------------

__global__ __launch_bounds__(256) void k_qkv(
    const float* __restrict__ x,
    const float* __restrict__ Wq, const float* __restrict__ bq,
    const float* __restrict__ Wk, const float* __restrict__ bk,
    const float* __restrict__ Wv, const float* __restrict__ bv,
    float* __restrict__ Q, float* __restrict__ K, float* __restrict__ V)
{
    __shared__ float WqT[DIM * DIM];
    __shared__ float WkT[DIM * DIM];
    __shared__ float WvT[DIM * DIM];
    __shared__ float xs[4][DIM];

    const int tid = threadIdx.x;
    for (int t = tid; t < DIM * DIM; t += 256) {
        int d = t >> 6, j = t & 63;
        WqT[j * DIM + d] = Wq[t];
        WkT[j * DIM + d] = Wk[t];
        WvT[j * DIM + d] = Wv[t];
    }
    __syncthreads();

    const int ln = tid >> 6;
    const int d  = tid & 63;
    const float bqv = bq[d], bkv = bk[d], bvv = bv[d];

    for (int base = blockIdx.x * 4; base < N_NODES; base += gridDim.x * 4) {
        __syncthreads();
        if (base + ln < N_NODES)
            xs[ln][d] = x[(size_t)base * DIM + tid];
        __syncthreads();
        int node = base + ln;
        if (node < N_NODES) {
            float aq = bqv, ak = bkv, av = bvv;
            #pragma unroll
            for (int j = 0; j < DIM; ++j) {
                float xv = xs[ln][j];
                aq += xv * WqT[j * DIM + d];
                ak += xv * WkT[j * DIM + d];
                av += xv * WvT[j * DIM + d];
            }
            Q[(size_t)node * DIM + d] = aq;
            K[(size_t)node * DIM + d] = ak;
            V[(size_t)node * DIM + d] = av;
        }
    }
}

// histogram of rows; also reset softmax scalars
__global__ __launch_bounds__(256) void k_hist(
    const int* __restrict__ eidx, int* __restrict__ counts,
    unsigned int* __restrict__ g_max, float* __restrict__ g_sum)
{
    int e = blockIdx.x * 256 + threadIdx.x;
    if (e < NE) atomicAdd(counts + eidx[e], 1);
    if (e == 0) { *g_max = 0u; *g_sum = 0.0f; }
}

// level-1 exclusive scan (per 256-block), partial result + block totals
__global__ __launch_bounds__(256) void k_scan1(
    const int* __restrict__ counts, int* __restrict__ offsets,
    int* __restrict__ bsums)
{
    __shared__ int tmp[256];
    int i = blockIdx.x * 256 + threadIdx.x;
    int v = (i < N_NODES) ? counts[i] : 0;
    tmp[threadIdx.x] = v;
    __syncthreads();
    #pragma unroll
    for (int off = 1; off < 256; off <<= 1) {
        int t = (threadIdx.x >= off) ? tmp[threadIdx.x - off] : 0;
        __syncthreads();
        tmp[threadIdx.x] += t;
        __syncthreads();
    }
    if (i < N_NODES) offsets[i] = tmp[threadIdx.x] - v;   // exclusive
    if (threadIdx.x == 255) bsums[blockIdx.x] = tmp[255];
}

// level-2: exclusive scan of block sums (single block)
__global__ __launch_bounds__(256) void k_scan2(int* __restrict__ bsums)
{
    __shared__ int tmp[256];
    int i = threadIdx.x;
    int v = (i < NSCAN_BLOCKS) ? bsums[i] : 0;
    tmp[i] = v;
    __syncthreads();
    #pragma unroll
    for (int off = 1; off < 256; off <<= 1) {
        int t = (i >= off) ? tmp[i - off] : 0;
        __syncthreads();
        tmp[i] += t;
        __syncthreads();
    }
    if (i < NSCAN_BLOCKS) bsums[i] = tmp[i] - v;
}

// level-3: add block offsets, copy to cursor, set offsets[N]
__global__ __launch_bounds__(256) void k_scan3(
    int* __restrict__ offsets, int* __restrict__ cursor,
    const int* __restrict__ bsums)
{
    int i = blockIdx.x * 256 + threadIdx.x;
    if (i < N_NODES) {
        int o = offsets[i] + bsums[i >> 8];
        offsets[i] = o;
        cursor[i]  = o;
    }
    if (i == 0) offsets[N_NODES] = NE;
}

__global__ __launch_bounds__(256) void k_fill(
    const int* __restrict__ eidx, int* __restrict__ cursor,
    int* __restrict__ bucket)
{
    int e = blockIdx.x * 256 + threadIdx.x;
    if (e < NE) {
        int pos = atomicAdd(cursor + eidx[e], 1);
        bucket[pos] = e;
    }
}

// one wave per node: logits for all its edges; wave-max -> global atomicMax
__global__ __launch_bounds__(256) void k_attn_csr(
    const int* __restrict__ bucket, const int* __restrict__ offsets,
    const int* __restrict__ eidx_col,
    const float* __restrict__ Q, const float* __restrict__ K,
    float* __restrict__ attn, unsigned int* __restrict__ g_max)
{
    const int lane = threadIdx.x & 63;
    const int n = (blockIdx.x * 256 + threadIdx.x) >> 6;
    if (n >= N_NODES) return;
    const float q = Q[(size_t)n * DIM + lane];
    const int s = offsets[n], t = offsets[n + 1];
    float wmax = -1e30f;
    for (int i = s; i < t; ++i) {
        int e = bucket[i];
        int c = eidx_col[e];
        float d = q * K[(size_t)c * DIM + lane];
        #pragma unroll
        for (int off = 32; off; off >>= 1) d += __shfl_xor(d, off);
        if (lane == 0) attn[e] = d;
        wmax = fmaxf(wmax, d);
    }
    if (lane == 0 && t > s) {
        unsigned int b = __float_as_uint(wmax);
        unsigned int key = (b & 0x80000000u) ? ~b : (b | 0x80000000u);
        atomicMax(g_max, key);
    }
}

// attn[e] = exp(attn[e]-max); g_sum += block partial
__global__ __launch_bounds__(256) void k_expsum(
    float* __restrict__ attn, const unsigned int* __restrict__ g_max,
    float* __restrict__ g_sum)
{
    __shared__ float red[4];
    unsigned int key = *g_max;
    unsigned int b = (key & 0x80000000u) ? (key & 0x7fffffffu) : ~key;
    float m = __uint_as_float(b);
    int e = blockIdx.x * 256 + threadIdx.x;
    float p = 0.0f;
    if (e < NE) {
        p = __expf(attn[e] - m);
        attn[e] = p;
    }
    #pragma unroll
    for (int off = 32; off; off >>= 1) p += __shfl_xor(p, off);
    if ((threadIdx.x & 63) == 0) red[threadIdx.x >> 6] = p;
    __syncthreads();
    if (threadIdx.x == 0)
        atomicAdd(g_sum, red[0] + red[1] + red[2] + red[3]);
}

// one wave per node: accumulate delta_x/delta_coord in registers, write once
__global__ __launch_bounds__(256) void k_gather(
    const int* __restrict__ bucket, const int* __restrict__ offsets,
    const int* __restrict__ eidx_col,
    const float* __restrict__ x, const float* __restrict__ coord,
    const float* __restrict__ V, const float* __restrict__ attn,
    const float* __restrict__ Wc, const float* __restrict__ bc,
    const float* __restrict__ g_sum,
    float* __restrict__ out_x, float* __restrict__ out_c)
{
    const int lane = threadIdx.x & 63;
    const int n = (blockIdx.x * 256 + threadIdx.x) >> 6;
    if (n >= N_NODES) return;
    const float inv = 1.0f / *g_sum;
    const float wcl = Wc[lane], bcl = bc[lane];
    const float cr = coord[(size_t)n * DIM + lane];
    const float xr = x[(size_t)n * DIM + lane];
    const int s = offsets[n], t = offsets[n + 1];
    float accx = 0.0f, accc = 0.0f;
    for (int i = s; i < t; ++i) {
        int e = bucket[i];
        int c = eidx_col[e];
        float w = attn[e] * inv;
        float cc = coord[(size_t)c * DIM + lane];
        float vv = V[(size_t)c * DIM + lane];
        float dxv = cr - cc;
        float d2 = dxv * dxv;
        #pragma unroll
        for (int off = 32; off; off >>= 1) d2 += __shfl_xor(d2, off);
        float dist = sqrtf(d2);
        accx += w * vv;
        accc += w * (dist * wcl + bcl) * dxv;
    }
    out_x[(size_t)n * DIM + lane] = xr + accx;
    out_c[(size_t)n * DIM + lane] = cr + accc;
}

extern "C" void kernel_launch(void* const* d_in, const int* in_sizes, int n_in,
                              void* d_out, int out_size, void* d_ws, size_t ws_size,
                              hipStream_t stream)
{
    const float* x     = (const float*)d_in[0];
    const float* coord = (const float*)d_in[1];
    const float* Wq    = (const float*)d_in[2];
    const float* bq    = (const float*)d_in[3];
    const float* Wk    = (const float*)d_in[4];
    const float* bk    = (const float*)d_in[5];
    const float* Wv    = (const float*)d_in[6];
    const float* bv    = (const float*)d_in[7];
    const float* Wc    = (const float*)d_in[8];
    const float* bc    = (const float*)d_in[9];
    const int*   eidx  = (const int*)d_in[10];
    const int*   eidx_col = eidx + NE;

    float* out   = (float*)d_out;
    float* ws    = (float*)d_ws;
    float* Q     = ws;
    float* K     = ws + (size_t)N_NODES * DIM;
    float* V     = ws + (size_t)2 * N_NODES * DIM;
    float* attn  = ws + (size_t)3 * N_NODES * DIM;
    int* counts  = (int*)(attn + NE);
    int* offsets = counts + N_NODES;
    int* cursor  = offsets + N_NODES + 1;
    int* bsums   = cursor + N_NODES;
    int* bucket  = bsums + 256;
    unsigned int* g_max = (unsigned int*)(bucket + NE);
    float* g_sum = (float*)(g_max + 1);

    float* out_x = out;
    float* out_c = out + (size_t)N_NODES * DIM;

    // CSR build
    hipMemsetAsync(counts, 0, (size_t)N_NODES * sizeof(int), stream);
    k_hist <<<(NE + 255) / 256, 256, 0, stream>>>(eidx, counts, g_max, g_sum);
    k_scan1<<<NSCAN_BLOCKS, 256, 0, stream>>>(counts, offsets, bsums);
    k_scan2<<<1, 256, 0, stream>>>(bsums);
    k_scan3<<<NSCAN_BLOCKS, 256, 0, stream>>>(offsets, cursor, bsums);
    k_fill <<<(NE + 255) / 256, 256, 0, stream>>>(eidx, cursor, bucket);

    // per-node QKV projections
    k_qkv<<<2048, 256, 0, stream>>>(x, Wq, bq, Wk, bk, Wv, bv, Q, K, V);

    // logits + global max (one wave per node)
    k_attn_csr<<<(N_NODES * 64 + 255) / 256, 256, 0, stream>>>(
        bucket, offsets, eidx_col, Q, K, attn, g_max);

    // exp + global sum
    k_expsum<<<(NE + 255) / 256, 256, 0, stream>>>(attn, g_max, g_sum);

    // register-accumulated gather + residual write (no atomics)
    k_gather<<<(N_NODES * 64 + 255) / 256, 256, 0, stream>>>(
        bucket, offsets, eidx_col, x, coord, V, attn, Wc, bc, g_sum,
        out_x, out_c);
}

// Round 3
// 529.890 us; speedup vs baseline: 1.8483x; 1.8483x over previous
//
#include <hip/hip_runtime.h>
#include <math.h>

#define N_NODES 50000
#define DIM 64
#define NE 800000
#define NSCAN_BLOCKS ((N_NODES + 255) / 256)   // 196
#define NWAVE_E 16384                          // waves in k_edge

// ---------------------------------------------------------------------------
// ws layout (floats / ints):
//   Q, K, V       : 3 × N*DIM floats
//   attn_perm     : NE floats   (CSR-position-indexed logits -> weights)
//   epos          : NE ints     (edge -> CSR position)
//   bucket_col    : NE ints     (CSR position -> col node)
//   counts        : N ints      (doubles as fill cursor)
//   offsets       : N+1 ints
//   bsums         : 256 ints
//   g_max (uint), g_sum (float)
// ---------------------------------------------------------------------------

// QKV projections: float4 LDS, 4 nodes/thread, block = 16 nodes
__global__ __launch_bounds__(256) void k_qkv(
    const float* __restrict__ x,
    const float* __restrict__ Wq, const float* __restrict__ bq,
    const float* __restrict__ Wk, const float* __restrict__ bk,
    const float* __restrict__ Wv, const float* __restrict__ bv,
    float* __restrict__ Q, float* __restrict__ K, float* __restrict__ V)
{
    // WT4[j2*64+d] = {W[d][4j2..4j2+3]}  (b128 reads, lane=d contiguous)
    __shared__ float4 WqT4[1024], WkT4[1024], WvT4[1024];
    __shared__ float4 xs4[16][16];

    const int tid = threadIdx.x;
    const float4* Wq4 = (const float4*)Wq;
    const float4* Wk4 = (const float4*)Wk;
    const float4* Wv4 = (const float4*)Wv;
    for (int t = tid; t < 1024; t += 256) {
        int d = t >> 4, j2 = t & 15;
        WqT4[j2 * 64 + d] = Wq4[t];
        WkT4[j2 * 64 + d] = Wk4[t];
        WvT4[j2 * 64 + d] = Wv4[t];
        (void)d;
    }

    const int wv = tid >> 6;    // wave 0..3
    const int d  = tid & 63;
    const float bqv = bq[d], bkv = bk[d], bvv = bv[d];
    const int base = blockIdx.x * 16;

    {   // stage 16 node rows as float4
        int r = tid >> 4, j2 = tid & 15;
        if (base + r < N_NODES)
            xs4[r][j2] = ((const float4*)x)[(size_t)(base + r) * 16 + j2];
    }
    __syncthreads();

    float aq[4], ak[4], av[4];
    #pragma unroll
    for (int r = 0; r < 4; ++r) { aq[r] = bqv; ak[r] = bkv; av[r] = bvv; }

    #pragma unroll
    for (int j2 = 0; j2 < 16; ++j2) {
        float4 wq = WqT4[j2 * 64 + d];
        float4 wk = WkT4[j2 * 64 + d];
        float4 wvv = WvT4[j2 * 64 + d];
        #pragma unroll
        for (int r = 0; r < 4; ++r) {
            float4 xv = xs4[wv * 4 + r][j2];
            aq[r] += xv.x * wq.x + xv.y * wq.y + xv.z * wq.z + xv.w * wq.w;
            ak[r] += xv.x * wk.x + xv.y * wk.y + xv.z * wk.z + xv.w * wk.w;
            av[r] += xv.x * wvv.x + xv.y * wvv.y + xv.z * wvv.z + xv.w * wvv.w;
        }
    }
    #pragma unroll
    for (int r = 0; r < 4; ++r) {
        int n = base + wv * 4 + r;
        if (n < N_NODES) {
            Q[(size_t)n * DIM + d] = aq[r];
            K[(size_t)n * DIM + d] = ak[r];
            V[(size_t)n * DIM + d] = av[r];
        }
    }
}

// histogram of rows; reset softmax scalars
__global__ __launch_bounds__(256) void k_hist(
    const int* __restrict__ eidx, int* __restrict__ counts,
    unsigned int* __restrict__ g_max, float* __restrict__ g_sum)
{
    int e = blockIdx.x * 256 + threadIdx.x;
    if (e < NE) atomicAdd(counts + eidx[e], 1);
    if (e == 0) { *g_max = 0u; *g_sum = 0.0f; }
}

__global__ __launch_bounds__(256) void k_scan1(
    const int* __restrict__ counts, int* __restrict__ offsets,
    int* __restrict__ bsums)
{
    __shared__ int tmp[256];
    int i = blockIdx.x * 256 + threadIdx.x;
    int v = (i < N_NODES) ? counts[i] : 0;
    tmp[threadIdx.x] = v;
    __syncthreads();
    #pragma unroll
    for (int off = 1; off < 256; off <<= 1) {
        int t = (threadIdx.x >= off) ? tmp[threadIdx.x - off] : 0;
        __syncthreads();
        tmp[threadIdx.x] += t;
        __syncthreads();
    }
    if (i < N_NODES) offsets[i] = tmp[threadIdx.x] - v;   // exclusive
    if (threadIdx.x == 255) bsums[blockIdx.x] = tmp[255];
}

__global__ __launch_bounds__(256) void k_scan2(int* __restrict__ bsums)
{
    __shared__ int tmp[256];
    int i = threadIdx.x;
    int v = (i < NSCAN_BLOCKS) ? bsums[i] : 0;
    tmp[i] = v;
    __syncthreads();
    #pragma unroll
    for (int off = 1; off < 256; off <<= 1) {
        int t = (i >= off) ? tmp[i - off] : 0;
        __syncthreads();
        tmp[i] += t;
        __syncthreads();
    }
    if (i < NSCAN_BLOCKS) bsums[i] = tmp[i] - v;
}

// finalize offsets; reset counts as the fill cursor
__global__ __launch_bounds__(256) void k_scan3(
    int* __restrict__ offsets, int* __restrict__ counts,
    const int* __restrict__ bsums)
{
    int i = blockIdx.x * 256 + threadIdx.x;
    if (i < N_NODES) {
        int o = offsets[i] + bsums[i >> 8];
        offsets[i] = o;
        counts[i]  = o;     // cursor
    }
    if (i == 0) offsets[N_NODES] = NE;
}

// fill: epos[e] = CSR position, bucket_col[pos] = col
__global__ __launch_bounds__(256) void k_fill(
    const int* __restrict__ eidx, int* __restrict__ cursor,
    int* __restrict__ epos, int* __restrict__ bucket_col)
{
    int e = blockIdx.x * 256 + threadIdx.x;
    if (e < NE) {
        int pos = atomicAdd(cursor + eidx[e], 1);
        epos[e] = pos;
        bucket_col[pos] = eidx[NE + e];
    }
}

// wave-per-edge logits, 2-edge interleave; store permuted; global max
__global__ __launch_bounds__(256) void k_edge(
    const int* __restrict__ eidx, const int* __restrict__ epos,
    const float* __restrict__ Q, const float* __restrict__ K,
    float* __restrict__ attnp, unsigned int* __restrict__ g_max)
{
    const int lane = threadIdx.x & 63;
    const int w = (blockIdx.x * 256 + threadIdx.x) >> 6;
    const int per = (NE + NWAVE_E - 1) / NWAVE_E;          // 49
    const int s = w * per;
    const int t = (s + per < NE) ? s + per : NE;
    if (s >= t) return;
    const int* __restrict__ col = eidx + NE;
    float wmax = -1e30f;
    int e = s;
    for (; e + 1 < t; e += 2) {
        int r0 = eidx[e],     c0 = col[e];
        int r1 = eidx[e + 1], c1 = col[e + 1];
        int p0 = epos[e], p1 = epos[e + 1];
        float d0 = Q[(size_t)r0 * DIM + lane] * K[(size_t)c0 * DIM + lane];
        float d1 = Q[(size_t)r1 * DIM + lane] * K[(size_t)c1 * DIM + lane];
        #pragma unroll
        for (int off = 32; off; off >>= 1) {
            d0 += __shfl_xor(d0, off);
            d1 += __shfl_xor(d1, off);
        }
        if (lane == 0) { attnp[p0] = d0; attnp[p1] = d1; }
        wmax = fmaxf(wmax, fmaxf(d0, d1));
    }
    for (; e < t; ++e) {
        int r0 = eidx[e], c0 = col[e], p0 = epos[e];
        float d0 = Q[(size_t)r0 * DIM + lane] * K[(size_t)c0 * DIM + lane];
        #pragma unroll
        for (int off = 32; off; off >>= 1) d0 += __shfl_xor(d0, off);
        if (lane == 0) attnp[p0] = d0;
        wmax = fmaxf(wmax, d0);
    }
    if (lane == 0) {
        unsigned int b = __float_as_uint(wmax);
        unsigned int key = (b & 0x80000000u) ? ~b : (b | 0x80000000u);
        atomicMax(g_max, key);
    }
}

// in-place exp over permuted logits + global sum (fully sequential)
__global__ __launch_bounds__(256) void k_expsum(
    float* __restrict__ attnp, const unsigned int* __restrict__ g_max,
    float* __restrict__ g_sum)
{
    __shared__ float red[4];
    unsigned int key = *g_max;
    unsigned int b = (key & 0x80000000u) ? (key & 0x7fffffffu) : ~key;
    float m = __uint_as_float(b);
    int i = blockIdx.x * 256 + threadIdx.x;
    float p = 0.0f;
    if (i < NE) {
        p = __expf(attnp[i] - m);
        attnp[i] = p;
    }
    #pragma unroll
    for (int off = 32; off; off >>= 1) p += __shfl_xor(p, off);
    if ((threadIdx.x & 63) == 0) red[threadIdx.x >> 6] = p;
    __syncthreads();
    if (threadIdx.x == 0)
        atomicAdd(g_sum, red[0] + red[1] + red[2] + red[3]);
}

// wave-per-node gather: sequential streams + coalesced row gathers
__global__ __launch_bounds__(256) void k_gather(
    const int* __restrict__ bucket_col, const int* __restrict__ offsets,
    const float* __restrict__ x, const float* __restrict__ coord,
    const float* __restrict__ V, const float* __restrict__ attnp,
    const float* __restrict__ Wc, const float* __restrict__ bc,
    const float* __restrict__ g_sum,
    float* __restrict__ out_x, float* __restrict__ out_c)
{
    const int lane = threadIdx.x & 63;
    const int n = (blockIdx.x * 256 + threadIdx.x) >> 6;
    if (n >= N_NODES) return;
    const float inv = 1.0f / *g_sum;
    const float wcl = Wc[lane], bcl = bc[lane];
    const float cr = coord[(size_t)n * DIM + lane];
    const float xr = x[(size_t)n * DIM + lane];
    const int s = offsets[n], t = offsets[n + 1];
    float accx = 0.0f, accc = 0.0f;
    int i = s;
    for (; i + 1 < t; i += 2) {
        int c0 = bucket_col[i], c1 = bucket_col[i + 1];
        float w0 = attnp[i] * inv, w1 = attnp[i + 1] * inv;
        float cc0 = coord[(size_t)c0 * DIM + lane];
        float vv0 = V[(size_t)c0 * DIM + lane];
        float cc1 = coord[(size_t)c1 * DIM + lane];
        float vv1 = V[(size_t)c1 * DIM + lane];
        float dx0 = cr - cc0, dx1 = cr - cc1;
        float d20 = dx0 * dx0, d21 = dx1 * dx1;
        #pragma unroll
        for (int off = 32; off; off >>= 1) {
            d20 += __shfl_xor(d20, off);
            d21 += __shfl_xor(d21, off);
        }
        float dist0 = sqrtf(d20), dist1 = sqrtf(d21);
        accx += w0 * vv0 + w1 * vv1;
        accc += w0 * (dist0 * wcl + bcl) * dx0;
        accc += w1 * (dist1 * wcl + bcl) * dx1;
    }
    for (; i < t; ++i) {
        int c0 = bucket_col[i];
        float w0 = attnp[i] * inv;
        float cc0 = coord[(size_t)c0 * DIM + lane];
        float vv0 = V[(size_t)c0 * DIM + lane];
        float dx0 = cr - cc0;
        float d20 = dx0 * dx0;
        #pragma unroll
        for (int off = 32; off; off >>= 1) d20 += __shfl_xor(d20, off);
        accx += w0 * vv0;
        accc += w0 * (sqrtf(d20) * wcl + bcl) * dx0;
    }
    out_x[(size_t)n * DIM + lane] = xr + accx;
    out_c[(size_t)n * DIM + lane] = cr + accc;
}

extern "C" void kernel_launch(void* const* d_in, const int* in_sizes, int n_in,
                              void* d_out, int out_size, void* d_ws, size_t ws_size,
                              hipStream_t stream)
{
    const float* x     = (const float*)d_in[0];
    const float* coord = (const float*)d_in[1];
    const float* Wq    = (const float*)d_in[2];
    const float* bq    = (const float*)d_in[3];
    const float* Wk    = (const float*)d_in[4];
    const float* bk    = (const float*)d_in[5];
    const float* Wv    = (const float*)d_in[6];
    const float* bv    = (const float*)d_in[7];
    const float* Wc    = (const float*)d_in[8];
    const float* bc    = (const float*)d_in[9];
    const int*   eidx  = (const int*)d_in[10];

    float* out   = (float*)d_out;
    float* ws    = (float*)d_ws;
    float* Q     = ws;
    float* K     = ws + (size_t)N_NODES * DIM;
    float* V     = ws + (size_t)2 * N_NODES * DIM;
    float* attnp = ws + (size_t)3 * N_NODES * DIM;
    int* epos       = (int*)(attnp + NE);
    int* bucket_col = epos + NE;
    int* counts     = bucket_col + NE;
    int* offsets    = counts + N_NODES;
    int* bsums      = offsets + N_NODES + 1;
    unsigned int* g_max = (unsigned int*)(bsums + 256);
    float* g_sum = (float*)(g_max + 1);

    float* out_x = out;
    float* out_c = out + (size_t)N_NODES * DIM;

    // CSR build
    hipMemsetAsync(counts, 0, (size_t)N_NODES * sizeof(int), stream);
    k_hist <<<(NE + 255) / 256, 256, 0, stream>>>(eidx, counts, g_max, g_sum);
    k_scan1<<<NSCAN_BLOCKS, 256, 0, stream>>>(counts, offsets, bsums);
    k_scan2<<<1, 256, 0, stream>>>(bsums);
    k_scan3<<<NSCAN_BLOCKS, 256, 0, stream>>>(offsets, counts, bsums);
    k_fill <<<(NE + 255) / 256, 256, 0, stream>>>(eidx, counts, epos, bucket_col);

    // per-node QKV projections (block = 16 nodes)
    k_qkv<<<(N_NODES + 15) / 16, 256, 0, stream>>>(
        x, Wq, bq, Wk, bk, Wv, bv, Q, K, V);

    // wave-per-edge logits -> permuted store + global max
    k_edge<<<NWAVE_E / 4, 256, 0, stream>>>(eidx, epos, Q, K, attnp, g_max);

    // in-place exp + global sum
    k_expsum<<<(NE + 255) / 256, 256, 0, stream>>>(attnp, g_max, g_sum);

    // wave-per-node gather + residual write (no atomics)
    k_gather<<<(N_NODES * 64 + 255) / 256, 256, 0, stream>>>(
        bucket_col, offsets, x, coord, V, attnp, Wc, bc, g_sum,
        out_x, out_c);
}

// Round 4
// 323.108 us; speedup vs baseline: 3.0312x; 1.6400x over previous
//
#include <hip/hip_runtime.h>
#include <math.h>

#define N_NODES 50000
#define DIM 64
#define NE 800000
#define NSCAN_BLOCKS ((N_NODES + 255) / 256)   // 196

static __device__ __forceinline__ float bf2f(unsigned short u) {
    return __uint_as_float(((unsigned int)u) << 16);
}
static __device__ __forceinline__ unsigned short f2bf(float f) {
    unsigned int u = __float_as_uint(f);
    u += 0x7fffu + ((u >> 16) & 1u);           // round-to-nearest-even
    return (unsigned short)(u >> 16);
}

// ---------------------------------------------------------------------------
// ws layout:
//   Qf      : N*DIM floats            (f32: read once, wave-uniform)
//   Kb,Vb,Cb: N*DIM ushorts each      (bf16: randomly gathered -> 1 line/row)
//   bucket_col : NE ints              (CSR position -> col node)
//   counts  : N ints (doubles as fill cursor)
//   offsets : N+1 ints
//   bsums   : 256 ints
//   wsum    : N floats (per-node unnormalized exp-sum partial)
//   S       : 1 float
// ---------------------------------------------------------------------------

// QKV projections (f32 in, Q f32 / K,V bf16 out) + coord->bf16 copy
__global__ __launch_bounds__(256) void k_qkv(
    const float* __restrict__ x, const float* __restrict__ coord,
    const float* __restrict__ Wq, const float* __restrict__ bq,
    const float* __restrict__ Wk, const float* __restrict__ bk,
    const float* __restrict__ Wv, const float* __restrict__ bv,
    float* __restrict__ Qf, unsigned short* __restrict__ Kb,
    unsigned short* __restrict__ Vb, unsigned short* __restrict__ Cb)
{
    __shared__ float4 WqT4[1024], WkT4[1024], WvT4[1024];
    __shared__ float4 xs4[16][16];

    const int tid = threadIdx.x;
    const float4* Wq4 = (const float4*)Wq;
    const float4* Wk4 = (const float4*)Wk;
    const float4* Wv4 = (const float4*)Wv;
    for (int t = tid; t < 1024; t += 256) {
        int d = t >> 4, j2 = t & 15;
        WqT4[j2 * 64 + d] = Wq4[t];
        WkT4[j2 * 64 + d] = Wk4[t];
        WvT4[j2 * 64 + d] = Wv4[t];
    }

    const int base = blockIdx.x * 16;

    // coord -> bf16 (1024 contiguous floats per block)
    for (int t = tid; t < 16 * DIM; t += 256) {
        int gn = base + (t >> 6);
        if (gn < N_NODES)
            Cb[(size_t)base * DIM + t] = f2bf(coord[(size_t)base * DIM + t]);
    }

    {   // stage 16 node rows of x as float4
        int r = tid >> 4, j2 = tid & 15;
        if (base + r < N_NODES)
            xs4[r][j2] = ((const float4*)x)[(size_t)(base + r) * 16 + j2];
    }
    __syncthreads();

    const int wv = tid >> 6;
    const int d  = tid & 63;
    const float bqv = bq[d], bkv = bk[d], bvv = bv[d];

    float aq[4], ak[4], av[4];
    #pragma unroll
    for (int r = 0; r < 4; ++r) { aq[r] = bqv; ak[r] = bkv; av[r] = bvv; }

    #pragma unroll
    for (int j2 = 0; j2 < 16; ++j2) {
        float4 wq = WqT4[j2 * 64 + d];
        float4 wk = WkT4[j2 * 64 + d];
        float4 wvv = WvT4[j2 * 64 + d];
        #pragma unroll
        for (int r = 0; r < 4; ++r) {
            float4 xv = xs4[wv * 4 + r][j2];
            aq[r] += xv.x * wq.x + xv.y * wq.y + xv.z * wq.z + xv.w * wq.w;
            ak[r] += xv.x * wk.x + xv.y * wk.y + xv.z * wk.z + xv.w * wk.w;
            av[r] += xv.x * wvv.x + xv.y * wvv.y + xv.z * wvv.z + xv.w * wvv.w;
        }
    }
    #pragma unroll
    for (int r = 0; r < 4; ++r) {
        int n = base + wv * 4 + r;
        if (n < N_NODES) {
            Qf[(size_t)n * DIM + d] = aq[r];
            Kb[(size_t)n * DIM + d] = f2bf(ak[r]);
            Vb[(size_t)n * DIM + d] = f2bf(av[r]);
        }
    }
}

__global__ __launch_bounds__(256) void k_hist(
    const int* __restrict__ eidx, int* __restrict__ counts)
{
    int e = blockIdx.x * 256 + threadIdx.x;
    if (e < NE) atomicAdd(counts + eidx[e], 1);
}

__global__ __launch_bounds__(256) void k_scan1(
    const int* __restrict__ counts, int* __restrict__ offsets,
    int* __restrict__ bsums)
{
    __shared__ int tmp[256];
    int i = blockIdx.x * 256 + threadIdx.x;
    int v = (i < N_NODES) ? counts[i] : 0;
    tmp[threadIdx.x] = v;
    __syncthreads();
    #pragma unroll
    for (int off = 1; off < 256; off <<= 1) {
        int t = (threadIdx.x >= off) ? tmp[threadIdx.x - off] : 0;
        __syncthreads();
        tmp[threadIdx.x] += t;
        __syncthreads();
    }
    if (i < N_NODES) offsets[i] = tmp[threadIdx.x] - v;   // exclusive
    if (threadIdx.x == 255) bsums[blockIdx.x] = tmp[255];
}

__global__ __launch_bounds__(256) void k_scan2(int* __restrict__ bsums)
{
    __shared__ int tmp[256];
    int i = threadIdx.x;
    int v = (i < NSCAN_BLOCKS) ? bsums[i] : 0;
    tmp[i] = v;
    __syncthreads();
    #pragma unroll
    for (int off = 1; off < 256; off <<= 1) {
        int t = (i >= off) ? tmp[i - off] : 0;
        __syncthreads();
        tmp[i] += t;
        __syncthreads();
    }
    if (i < NSCAN_BLOCKS) bsums[i] = tmp[i] - v;
}

__global__ __launch_bounds__(256) void k_scan3(
    int* __restrict__ offsets, int* __restrict__ counts,
    const int* __restrict__ bsums)
{
    int i = blockIdx.x * 256 + threadIdx.x;
    if (i < N_NODES) {
        int o = offsets[i] + bsums[i >> 8];
        offsets[i] = o;
        counts[i]  = o;     // cursor for fill
    }
    if (i == 0) offsets[N_NODES] = NE;
}

__global__ __launch_bounds__(256) void k_fill(
    const int* __restrict__ eidx, int* __restrict__ cursor,
    int* __restrict__ bucket_col)
{
    int e = blockIdx.x * 256 + threadIdx.x;
    if (e < NE) {
        int pos = atomicAdd(cursor + eidx[e], 1);
        bucket_col[pos] = eidx[NE + e];
    }
}

// ONE pass over edges in CSR order: logit -> exp -> unnormalized accumulate.
// wave per node, lane = dim, 2-edge interleave. Writes acc into d_out.
__global__ __launch_bounds__(256) void k_edge_fused(
    const int* __restrict__ bucket_col, const int* __restrict__ offsets,
    const float* __restrict__ Qf, const unsigned short* __restrict__ Kb,
    const unsigned short* __restrict__ Vb, const unsigned short* __restrict__ Cb,
    const float* __restrict__ coord,
    const float* __restrict__ Wc, const float* __restrict__ bc,
    float* __restrict__ out_x, float* __restrict__ out_c,
    float* __restrict__ wsum)
{
    const int lane = threadIdx.x & 63;
    const int n = (blockIdx.x * 256 + threadIdx.x) >> 6;
    if (n >= N_NODES) return;
    const float q   = Qf[(size_t)n * DIM + lane];
    const float cr  = coord[(size_t)n * DIM + lane];
    const float wcl = Wc[lane], bcl = bc[lane];
    const int s = offsets[n], t = offsets[n + 1];
    float accx = 0.0f, accc = 0.0f, psum = 0.0f;
    int i = s;
    for (; i + 1 < t; i += 2) {
        int c0 = bucket_col[i], c1 = bucket_col[i + 1];
        size_t b0 = (size_t)c0 * DIM + lane;
        size_t b1 = (size_t)c1 * DIM + lane;
        float k0 = bf2f(Kb[b0]), k1 = bf2f(Kb[b1]);
        float v0 = bf2f(Vb[b0]), v1 = bf2f(Vb[b1]);
        float cc0 = bf2f(Cb[b0]), cc1 = bf2f(Cb[b1]);
        float d0 = q * k0, d1 = q * k1;
        float dx0 = cr - cc0, dx1 = cr - cc1;
        float e0 = dx0 * dx0, e1 = dx1 * dx1;
        #pragma unroll
        for (int off = 32; off; off >>= 1) {
            d0 += __shfl_xor(d0, off);
            d1 += __shfl_xor(d1, off);
            e0 += __shfl_xor(e0, off);
            e1 += __shfl_xor(e1, off);
        }
        float p0 = __expf(d0), p1 = __expf(d1);
        psum += p0 + p1;
        accx += p0 * v0 + p1 * v1;
        accc += p0 * (sqrtf(e0) * wcl + bcl) * dx0
              + p1 * (sqrtf(e1) * wcl + bcl) * dx1;
    }
    for (; i < t; ++i) {
        int c0 = bucket_col[i];
        size_t b0 = (size_t)c0 * DIM + lane;
        float k0 = bf2f(Kb[b0]);
        float v0 = bf2f(Vb[b0]);
        float cc0 = bf2f(Cb[b0]);
        float d0 = q * k0;
        float dx0 = cr - cc0;
        float e0 = dx0 * dx0;
        #pragma unroll
        for (int off = 32; off; off >>= 1) {
            d0 += __shfl_xor(d0, off);
            e0 += __shfl_xor(e0, off);
        }
        float p0 = __expf(d0);
        psum += p0;
        accx += p0 * v0;
        accc += p0 * (sqrtf(e0) * wcl + bcl) * dx0;
    }
    out_x[(size_t)n * DIM + lane] = accx;   // unnormalized
    out_c[(size_t)n * DIM + lane] = accc;
    if (lane == 0) wsum[n] = psum;          // post-butterfly: lane-uniform
}

// deterministic fixed-tree reduction of wsum -> S (single block)
__global__ __launch_bounds__(1024) void k_redsum(
    const float* __restrict__ wsum, float* __restrict__ S)
{
    __shared__ float red[16];
    float a = 0.0f;
    for (int i = threadIdx.x; i < N_NODES; i += 1024) a += wsum[i];
    #pragma unroll
    for (int off = 32; off; off >>= 1) a += __shfl_xor(a, off);
    if ((threadIdx.x & 63) == 0) red[threadIdx.x >> 6] = a;
    __syncthreads();
    if (threadIdx.x == 0) {
        float s = 0.0f;
        #pragma unroll
        for (int w = 0; w < 16; ++w) s += red[w];
        *S = s;
    }
}

// out = residual + out * (1/S), vectorized float4
__global__ __launch_bounds__(256) void k_finalize(
    const float* __restrict__ x, const float* __restrict__ coord,
    const float* __restrict__ S, float* __restrict__ out)
{
    const float inv = 1.0f / *S;
    const int nd4 = (N_NODES * DIM) / 4;      // 800000
    const float4* x4 = (const float4*)x;
    const float4* c4 = (const float4*)coord;
    float4* o4 = (float4*)out;
    for (int i = blockIdx.x * 256 + threadIdx.x; i < 2 * nd4;
         i += gridDim.x * 256) {
        float4 r = (i < nd4) ? x4[i] : c4[i - nd4];
        float4 a = o4[i];
        a.x = r.x + a.x * inv;
        a.y = r.y + a.y * inv;
        a.z = r.z + a.z * inv;
        a.w = r.w + a.w * inv;
        o4[i] = a;
    }
}

extern "C" void kernel_launch(void* const* d_in, const int* in_sizes, int n_in,
                              void* d_out, int out_size, void* d_ws, size_t ws_size,
                              hipStream_t stream)
{
    const float* x     = (const float*)d_in[0];
    const float* coord = (const float*)d_in[1];
    const float* Wq    = (const float*)d_in[2];
    const float* bq    = (const float*)d_in[3];
    const float* Wk    = (const float*)d_in[4];
    const float* bk    = (const float*)d_in[5];
    const float* Wv    = (const float*)d_in[6];
    const float* bv    = (const float*)d_in[7];
    const float* Wc    = (const float*)d_in[8];
    const float* bc    = (const float*)d_in[9];
    const int*   eidx  = (const int*)d_in[10];

    float* out = (float*)d_out;
    float* ws  = (float*)d_ws;

    float* Qf = ws;
    unsigned short* Kb = (unsigned short*)(Qf + (size_t)N_NODES * DIM);
    unsigned short* Vb = Kb + (size_t)N_NODES * DIM;
    unsigned short* Cb = Vb + (size_t)N_NODES * DIM;
    int* bucket_col = (int*)(Cb + (size_t)N_NODES * DIM);
    int* counts  = bucket_col + NE;
    int* offsets = counts + N_NODES;
    int* bsums   = offsets + N_NODES + 1;
    float* wsum  = (float*)(bsums + 256);
    float* S     = wsum + N_NODES;

    float* out_x = out;
    float* out_c = out + (size_t)N_NODES * DIM;

    // CSR build (row-bucketed column list)
    hipMemsetAsync(counts, 0, (size_t)N_NODES * sizeof(int), stream);
    k_hist <<<(NE + 255) / 256, 256, 0, stream>>>(eidx, counts);
    k_scan1<<<NSCAN_BLOCKS, 256, 0, stream>>>(counts, offsets, bsums);
    k_scan2<<<1, 256, 0, stream>>>(bsums);
    k_scan3<<<NSCAN_BLOCKS, 256, 0, stream>>>(offsets, counts, bsums);
    k_fill <<<(NE + 255) / 256, 256, 0, stream>>>(eidx, counts, bucket_col);

    // node projections + bf16 packing
    k_qkv<<<(N_NODES + 15) / 16, 256, 0, stream>>>(
        x, coord, Wq, bq, Wk, bk, Wv, bv, Qf, Kb, Vb, Cb);

    // single fused edge pass (unnormalized), acc -> d_out, Σp -> wsum
    k_edge_fused<<<(N_NODES * 64 + 255) / 256, 256, 0, stream>>>(
        bucket_col, offsets, Qf, Kb, Vb, Cb, coord, Wc, bc,
        out_x, out_c, wsum);

    // deterministic global sum, then normalize + residual
    k_redsum<<<1, 1024, 0, stream>>>(wsum, S);
    k_finalize<<<2048, 256, 0, stream>>>(x, coord, S, out);
}